// Round 7
// baseline (163.019 us; speedup 1.0000x reference)
//
#include <hip/hip_runtime.h>
#include <math.h>

#define N_PTS 262144
#define WIDTH 256

// fp32 Jacobi rotation on symmetric 3x3, updating eigenvector matrix columns
__device__ __forceinline__ void jrot(float &app, float &aqq, float &apq,
                                     float &arp, float &arq,
                                     float &vp0, float &vq0,
                                     float &vp1, float &vq1,
                                     float &vp2, float &vq2)
{
    float a = apq;
    if (fabsf(a) < 1e-20f) return;
    float theta = (aqq - app) / (2.0f * a);
    float tt = copysignf(1.0f, theta) / (fabsf(theta) + sqrtf(1.0f + theta * theta));
    float c = 1.0f / sqrtf(1.0f + tt * tt);
    float s = tt * c;
    app -= tt * a;
    aqq += tt * a;
    apq = 0.0f;
    float rp = arp, rq = arq;
    arp = c * rp - s * rq;
    arq = s * rp + c * rq;
    float t0p = vp0, t0q = vq0; vp0 = c * t0p - s * t0q; vq0 = s * t0p + c * t0q;
    float t1p = vp1, t1q = vq1; vp1 = c * t1p - s * t1q; vq1 = s * t1p + c * t1q;
    float t2p = vp2, t2q = vq2; vp2 = c * t2p - s * t2q; vq2 = s * t2p + c * t2q;
}

// 2 waves per 64 points: wave h of a pair covers K-columns [128h,128h+128)
// (weight index stays wave-uniform -> scalar loads). Each wave streams its
// half through a private 64x17 LDS tile, barrier-free; partials combine via
// LDS + one __syncthreads; each wave epilogues 32 points.
// 2048 blocks x 4 waves = 8192 waves -> 32 waves/CU (2x previous rounds).
__global__ __launch_bounds__(256, 8) void so3_kernel(
    const float* __restrict__ x,
    const float* __restrict__ fw,
    const float* __restrict__ fb,
    float* __restrict__ out)
{
    __shared__ float xs[4][64][17];      // 17,408 B -> 9 blocks/CU by LDS
    const int tid  = threadIdx.x;
    const int lane = tid & 63;
    const int w    = tid >> 6;           // 0..3
    const int pair = w >> 1;             // 0..1
    const int h    = w & 1;              // K-half
    const int r0   = ((blockIdx.x << 1) + pair) << 6;   // pair's first point
    const int cb   = h << 7;             // column base: 0 or 128
    float (*tile)[17] = xs[w];

    const int a = lane >> 2;             // row sub-index 0..15
    const int b = lane & 3;              // float4 slot in 16-col chunk

    float y[9];
#pragma unroll
    for (int j = 0; j < 9; ++j) y[j] = 0.f;

    // prologue: prefetch chunk 0 of this wave's column half
    float4 pre[4];
#pragma unroll
    for (int i = 0; i < 4; ++i) {
        const int row = (i << 4) + a;
        pre[i] = *reinterpret_cast<const float4*>(
            x + (size_t)(r0 + row) * WIDTH + cb + (b << 2));
    }

    for (int kc = 0; kc < 8; ++kc) {
        // write prefetched chunk to this wave's tile (<=2-way banks: free)
#pragma unroll
        for (int i = 0; i < 4; ++i) {
            const int row = (i << 4) + a;
            const int c   = b << 2;
            tile[row][c + 0] = pre[i].x;
            tile[row][c + 1] = pre[i].y;
            tile[row][c + 2] = pre[i].z;
            tile[row][c + 3] = pre[i].w;
        }

        // issue next chunk's loads; they fly over this chunk's compute
        if (kc < 7) {
            const int k0n = cb + ((kc + 1) << 4);
#pragma unroll
            for (int i = 0; i < 4; ++i) {
                const int row = (i << 4) + a;
                pre[i] = *reinterpret_cast<const float4*>(
                    x + (size_t)(r0 + row) * WIDTH + k0n + (b << 2));
            }
        }

        const int k0 = cb + (kc << 4);
#pragma unroll
        for (int kk = 0; kk < 16; ++kk) {
            const float xv = tile[lane][kk];   // bank (lane+kk+16(lane&1))%32: 2-way, free
            const int k = k0 + kk;             // wave-uniform -> scalar s_loads
#pragma unroll
            for (int j = 0; j < 9; ++j)
                y[j] = fmaf(xv, fw[j * WIDTH + k], y[j]);
        }
    }

    // stash partial y into own tile (cols 0..8), combine across the pair
#pragma unroll
    for (int j = 0; j < 9; ++j) tile[lane][j] = y[j];
    __syncthreads();

    // each wave finishes 32 of the pair's 64 points (lanes 32..63 duplicate)
    const int p2 = (h << 5) + (lane & 31);
    float (*tA)[17] = xs[(pair << 1) + 0];
    float (*tB)[17] = xs[(pair << 1) + 1];

    float z[9];
#pragma unroll
    for (int j = 0; j < 9; ++j)
        z[j] = tA[p2][j] + tB[p2][j] + fb[j];

    // ---- fp32 3x3 special Procrustes:  R = U diag(1,1,det) V^T ----
    const float m00 = z[0], m01 = z[1], m02 = z[2];
    const float m10 = z[3], m11 = z[4], m12 = z[5];
    const float m20 = z[6], m21 = z[7], m22 = z[8];

    float a00 = m00*m00 + m10*m10 + m20*m20;
    float a01 = m00*m01 + m10*m11 + m20*m21;
    float a02 = m00*m02 + m10*m12 + m20*m22;
    float a11 = m01*m01 + m11*m11 + m21*m21;
    float a12 = m01*m02 + m11*m12 + m21*m22;
    float a22 = m02*m02 + m12*m12 + m22*m22;

    float v[3][3] = { {1,0,0}, {0,1,0}, {0,0,1} };

#pragma unroll
    for (int sw = 0; sw < 5; ++sw) {
        jrot(a00, a11, a01, a02, a12,
             v[0][0], v[0][1], v[1][0], v[1][1], v[2][0], v[2][1]);
        jrot(a00, a22, a02, a01, a12,
             v[0][0], v[0][2], v[1][0], v[1][2], v[2][0], v[2][2]);
        jrot(a11, a22, a12, a01, a02,
             v[0][1], v[0][2], v[1][1], v[1][2], v[2][1], v[2][2]);
    }

    float d0 = a00, d1 = a11, d2 = a22, tmp;
    if (d0 < d1) { tmp=d0; d0=d1; d1=tmp;
        tmp=v[0][0]; v[0][0]=v[0][1]; v[0][1]=tmp;
        tmp=v[1][0]; v[1][0]=v[1][1]; v[1][1]=tmp;
        tmp=v[2][0]; v[2][0]=v[2][1]; v[2][1]=tmp; }
    if (d0 < d2) { tmp=d0; d0=d2; d2=tmp;
        tmp=v[0][0]; v[0][0]=v[0][2]; v[0][2]=tmp;
        tmp=v[1][0]; v[1][0]=v[1][2]; v[1][2]=tmp;
        tmp=v[2][0]; v[2][0]=v[2][2]; v[2][2]=tmp; }
    if (d1 < d2) { tmp=d1; d1=d2; d2=tmp;
        tmp=v[0][1]; v[0][1]=v[0][2]; v[0][2]=tmp;
        tmp=v[1][1]; v[1][1]=v[1][2]; v[1][2]=tmp;
        tmp=v[2][1]; v[2][1]=v[2][2]; v[2][2]=tmp; }

    const float v1x = v[0][0], v1y = v[1][0], v1z = v[2][0];
    const float v2x = v[0][1], v2y = v[1][1], v2z = v[2][1];

    // u1 = normalize(M v1)
    float u1x = m00*v1x + m01*v1y + m02*v1z;
    float u1y = m10*v1x + m11*v1y + m12*v1z;
    float u1z = m20*v1x + m21*v1y + m22*v1z;
    float inv1 = 1.0f / (sqrtf(u1x*u1x + u1y*u1y + u1z*u1z) + 1e-30f);
    u1x *= inv1; u1y *= inv1; u1z *= inv1;

    // u2 = normalize(M v2 - (u1 . M v2) u1)
    float u2x = m00*v2x + m01*v2y + m02*v2z;
    float u2y = m10*v2x + m11*v2y + m12*v2z;
    float u2z = m20*v2x + m21*v2y + m22*v2z;
    const float d12 = u1x*u2x + u1y*u2y + u1z*u2z;
    u2x -= d12*u1x; u2y -= d12*u1y; u2z -= d12*u1z;
    float inv2 = 1.0f / (sqrtf(u2x*u2x + u2y*u2y + u2z*u2z) + 1e-30f);
    u2x *= inv2; u2y *= inv2; u2z *= inv2;

    // u3 = u1 x u2 ; v3 = v1 x v2
    const float u3x = u1y*u2z - u1z*u2y;
    const float u3y = u1z*u2x - u1x*u2z;
    const float u3z = u1x*u2y - u1y*u2x;
    const float v3x = v1y*v2z - v1z*v2y;
    const float v3y = v1z*v2x - v1x*v2z;
    const float v3z = v1x*v2y - v1y*v2x;

    float r[9];
    r[0] = u1x*v1x + u2x*v2x + u3x*v3x;
    r[1] = u1x*v1y + u2x*v2y + u3x*v3y;
    r[2] = u1x*v1z + u2x*v2z + u3x*v3z;
    r[3] = u1y*v1x + u2y*v2x + u3y*v3x;
    r[4] = u1y*v1y + u2y*v2y + u3y*v3y;
    r[5] = u1y*v1z + u2y*v2z + u3y*v3z;
    r[6] = u1z*v1x + u2z*v2x + u3z*v3x;
    r[7] = u1z*v1y + u2z*v2y + u3z*v3y;
    r[8] = u1z*v1z + u2z*v2z + u3z*v3z;

    if ((lane & 32) == 0) {              // lanes 0..31 write (32..63 duplicate)
        float* o = out + (size_t)(r0 + p2) * 9;
#pragma unroll
        for (int j = 0; j < 9; ++j) o[j] = r[j];
    }
}

extern "C" void kernel_launch(void* const* d_in, const int* in_sizes, int n_in,
                              void* d_out, int out_size, void* d_ws, size_t ws_size,
                              hipStream_t stream) {
    const float* x  = (const float*)d_in[0];
    const float* fw = (const float*)d_in[1];
    const float* fb = (const float*)d_in[2];
    float* out = (float*)d_out;
    dim3 grid(N_PTS / 128), block(256);   // 2 wave-pairs/block, 64 pts/pair
    hipLaunchKernelGGL(so3_kernel, grid, block, 0, stream, x, fw, fb, out);
}

// Round 8
// 129.478 us; speedup vs baseline: 1.2590x; 1.2590x over previous
//
#include <hip/hip_runtime.h>
#include <math.h>

#define N_PTS 262144
#define WIDTH 256

// fp32 Jacobi rotation on symmetric 3x3, updating eigenvector matrix columns
__device__ __forceinline__ void jrot(float &app, float &aqq, float &apq,
                                     float &arp, float &arq,
                                     float &vp0, float &vq0,
                                     float &vp1, float &vq1,
                                     float &vp2, float &vq2)
{
    float a = apq;
    if (fabsf(a) < 1e-20f) return;
    float theta = (aqq - app) / (2.0f * a);
    float tt = copysignf(1.0f, theta) / (fabsf(theta) + sqrtf(1.0f + theta * theta));
    float c = 1.0f / sqrtf(1.0f + tt * tt);
    float s = tt * c;
    app -= tt * a;
    aqq += tt * a;
    apq = 0.0f;
    float rp = arp, rq = arq;
    arp = c * rp - s * rq;
    arq = s * rp + c * rq;
    float t0p = vp0, t0q = vq0; vp0 = c * t0p - s * t0q; vq0 = s * t0p + c * t0q;
    float t1p = vp1, t1q = vq1; vp1 = c * t1p - s * t1q; vq1 = s * t1p + c * t1q;
    float t2p = vp2, t2q = vq2; vp2 = c * t2p - s * t2q; vq2 = s * t2p + c * t2q;
}

// High-occupancy variant of the R4 structure: one wave owns 32 points
// (tile [32][33] = 4.2 KB -> 16.9 KB/block -> 9 blocks/CU by LDS).
// Lanes l and l+32 duplicate the same row (k stays wave-uniform -> scalar
// W loads; LDS reads broadcast). Barrier-free private tiles, register
// prefetch double-buffer, 32-col (128 B line) chunks.
__global__ __launch_bounds__(256, 8) void so3_kernel(
    const float* __restrict__ x,
    const float* __restrict__ fw,
    const float* __restrict__ fb,
    float* __restrict__ out)
{
    __shared__ float xs[4][32][33];      // 16,896 B per block
    const int lane = threadIdx.x & 63;
    const int w    = threadIdx.x >> 6;
    const int r0   = (((blockIdx.x << 2) + w) << 5);   // wave's first point
    float (*tile)[33] = xs[w];

    float y[9];
#pragma unroll
    for (int j = 0; j < 9; ++j) y[j] = 0.f;

    // prologue: prefetch chunk 0 (32 rows x 32 cols = 4 KB, 4 instrs)
    float4 pre[4];
#pragma unroll
    for (int i = 0; i < 4; ++i) {
        const int f   = (i << 6) + lane;   // float4 idx 0..255
        const int row = f >> 3;            // 8 float4 per row
        const int c4  = f & 7;
        pre[i] = *reinterpret_cast<const float4*>(
            x + (size_t)(r0 + row) * WIDTH + (c4 << 2));
    }

    for (int kc = 0; kc < 8; ++kc) {
        // write prefetched chunk to this wave's tile
        // banks (row + 4b + c)%32 spread ~<=3-way: effectively free
#pragma unroll
        for (int i = 0; i < 4; ++i) {
            const int f   = (i << 6) + lane;
            const int row = f >> 3;
            const int c   = (f & 7) << 2;
            tile[row][c + 0] = pre[i].x;
            tile[row][c + 1] = pre[i].y;
            tile[row][c + 2] = pre[i].z;
            tile[row][c + 3] = pre[i].w;
        }

        // issue next chunk's loads; they fly over this chunk's compute
        if (kc < 7) {
            const int k0n = (kc + 1) << 5;
#pragma unroll
            for (int i = 0; i < 4; ++i) {
                const int f   = (i << 6) + lane;
                const int row = f >> 3;
                const int c4  = f & 7;
                pre[i] = *reinterpret_cast<const float4*>(
                    x + (size_t)(r0 + row) * WIDTH + k0n + (c4 << 2));
            }
        }

        const int k0 = kc << 5;
#pragma unroll
        for (int kk = 0; kk < 32; ++kk) {
            // lanes 0..31 distinct banks; lanes 32..63 same addr -> broadcast
            const float xv = tile[lane & 31][kk];
            const int k = k0 + kk;               // wave-uniform -> s_loads
#pragma unroll
            for (int j = 0; j < 9; ++j)
                y[j] = fmaf(xv, fw[j * WIDTH + k], y[j]);
        }
    }

#pragma unroll
    for (int j = 0; j < 9; ++j) y[j] += fb[j];

    // ---- fp32 3x3 special Procrustes:  R = U diag(1,1,det) V^T ----
    const float m00 = y[0], m01 = y[1], m02 = y[2];
    const float m10 = y[3], m11 = y[4], m12 = y[5];
    const float m20 = y[6], m21 = y[7], m22 = y[8];

    float a00 = m00*m00 + m10*m10 + m20*m20;
    float a01 = m00*m01 + m10*m11 + m20*m21;
    float a02 = m00*m02 + m10*m12 + m20*m22;
    float a11 = m01*m01 + m11*m11 + m21*m21;
    float a12 = m01*m02 + m11*m12 + m21*m22;
    float a22 = m02*m02 + m12*m12 + m22*m22;

    float v[3][3] = { {1,0,0}, {0,1,0}, {0,0,1} };

#pragma unroll
    for (int sw = 0; sw < 5; ++sw) {
        jrot(a00, a11, a01, a02, a12,
             v[0][0], v[0][1], v[1][0], v[1][1], v[2][0], v[2][1]);
        jrot(a00, a22, a02, a01, a12,
             v[0][0], v[0][2], v[1][0], v[1][2], v[2][0], v[2][2]);
        jrot(a11, a22, a12, a01, a02,
             v[0][1], v[0][2], v[1][1], v[1][2], v[2][1], v[2][2]);
    }

    float d0 = a00, d1 = a11, d2 = a22, tmp;
    if (d0 < d1) { tmp=d0; d0=d1; d1=tmp;
        tmp=v[0][0]; v[0][0]=v[0][1]; v[0][1]=tmp;
        tmp=v[1][0]; v[1][0]=v[1][1]; v[1][1]=tmp;
        tmp=v[2][0]; v[2][0]=v[2][1]; v[2][1]=tmp; }
    if (d0 < d2) { tmp=d0; d0=d2; d2=tmp;
        tmp=v[0][0]; v[0][0]=v[0][2]; v[0][2]=tmp;
        tmp=v[1][0]; v[1][0]=v[1][2]; v[1][2]=tmp;
        tmp=v[2][0]; v[2][0]=v[2][2]; v[2][2]=tmp; }
    if (d1 < d2) { tmp=d1; d1=d2; d2=tmp;
        tmp=v[0][1]; v[0][1]=v[0][2]; v[0][2]=tmp;
        tmp=v[1][1]; v[1][1]=v[1][2]; v[1][2]=tmp;
        tmp=v[2][1]; v[2][1]=v[2][2]; v[2][2]=tmp; }

    const float v1x = v[0][0], v1y = v[1][0], v1z = v[2][0];
    const float v2x = v[0][1], v2y = v[1][1], v2z = v[2][1];

    // u1 = normalize(M v1)
    float u1x = m00*v1x + m01*v1y + m02*v1z;
    float u1y = m10*v1x + m11*v1y + m12*v1z;
    float u1z = m20*v1x + m21*v1y + m22*v1z;
    float inv1 = 1.0f / (sqrtf(u1x*u1x + u1y*u1y + u1z*u1z) + 1e-30f);
    u1x *= inv1; u1y *= inv1; u1z *= inv1;

    // u2 = normalize(M v2 - (u1 . M v2) u1)
    float u2x = m00*v2x + m01*v2y + m02*v2z;
    float u2y = m10*v2x + m11*v2y + m12*v2z;
    float u2z = m20*v2x + m21*v2y + m22*v2z;
    const float d12 = u1x*u2x + u1y*u2y + u1z*u2z;
    u2x -= d12*u1x; u2y -= d12*u1y; u2z -= d12*u1z;
    float inv2 = 1.0f / (sqrtf(u2x*u2x + u2y*u2y + u2z*u2z) + 1e-30f);
    u2x *= inv2; u2y *= inv2; u2z *= inv2;

    // u3 = u1 x u2 ; v3 = v1 x v2
    const float u3x = u1y*u2z - u1z*u2y;
    const float u3y = u1z*u2x - u1x*u2z;
    const float u3z = u1x*u2y - u1y*u2x;
    const float v3x = v1y*v2z - v1z*v2y;
    const float v3y = v1z*v2x - v1x*v2z;
    const float v3z = v1x*v2y - v1y*v2x;

    float r[9];
    r[0] = u1x*v1x + u2x*v2x + u3x*v3x;
    r[1] = u1x*v1y + u2x*v2y + u3x*v3y;
    r[2] = u1x*v1z + u2x*v2z + u3x*v3z;
    r[3] = u1y*v1x + u2y*v2x + u3y*v3x;
    r[4] = u1y*v1y + u2y*v2y + u3y*v3y;
    r[5] = u1y*v1z + u2y*v2z + u3y*v3y*0.0f + u2y*v2z*0.0f + (u1y*v1z + u2y*v2z + u3y*v3z) - (u1y*v1z + u2y*v2z);  // placeholder avoided below
    r[5] = u1y*v1z + u2y*v2z + u3y*v3z;
    r[6] = u1z*v1x + u2z*v2x + u3z*v3x;
    r[7] = u1z*v1y + u2z*v2y + u3z*v3y;
    r[8] = u1z*v1z + u2z*v2z + u3z*v3z;

    if (lane < 32) {                     // lanes 32..63 are duplicates
        float* o = out + (size_t)(r0 + lane) * 9;
#pragma unroll
        for (int j = 0; j < 9; ++j) o[j] = r[j];
    }
}

extern "C" void kernel_launch(void* const* d_in, const int* in_sizes, int n_in,
                              void* d_out, int out_size, void* d_ws, size_t ws_size,
                              hipStream_t stream) {
    const float* x  = (const float*)d_in[0];
    const float* fw = (const float*)d_in[1];
    const float* fb = (const float*)d_in[2];
    float* out = (float*)d_out;
    dim3 grid(N_PTS / 128), block(256);   // 4 waves/block, 32 points/wave
    hipLaunchKernelGGL(so3_kernel, grid, block, 0, stream, x, fw, fb, out);
}

// Round 9
// 83.287 us; speedup vs baseline: 1.9573x; 1.5546x over previous
//
#include <hip/hip_runtime.h>
#include <math.h>

#define N_PTS 262144
#define WIDTH 256

// fp32 Jacobi rotation on symmetric 3x3, updating eigenvector matrix columns
__device__ __forceinline__ void jrot(float &app, float &aqq, float &apq,
                                     float &arp, float &arq,
                                     float &vp0, float &vq0,
                                     float &vp1, float &vq1,
                                     float &vp2, float &vq2)
{
    float a = apq;
    if (fabsf(a) < 1e-20f) return;
    float theta = (aqq - app) / (2.0f * a);
    float tt = copysignf(1.0f, theta) / (fabsf(theta) + sqrtf(1.0f + theta * theta));
    float c = 1.0f / sqrtf(1.0f + tt * tt);
    float s = tt * c;
    app -= tt * a;
    aqq += tt * a;
    apq = 0.0f;
    float rp = arp, rq = arq;
    arp = c * rp - s * rq;
    arq = s * rp + c * rq;
    float t0p = vp0, t0q = vq0; vp0 = c * t0p - s * t0q; vq0 = s * t0p + c * t0q;
    float t1p = vp1, t1q = vq1; vp1 = c * t1p - s * t1q; vq1 = s * t1p + c * t1q;
    float t2p = vp2, t2q = vq2; vp2 = c * t2p - s * t2q; vq2 = s * t2p + c * t2q;
}

// Sequential-fetch design: block owns 256 consecutive rows = 256 KB read as
// one contiguous stream in 4 phases of 64 full rows (64 KB each).
// Phase p: stage rows [64p,64p+64) -> tile; wave w computes partial dots for
// all 64 staged points over columns [64w,64w+64) (k wave-uniform -> W via
// s_loads); partials combine in LDS; wave p keeps y for its 64 points in
// registers. After 4 phases thread t holds y of point r0+t; fp32 Procrustes;
// coalesced store. LDS 75.3 KB -> 2 blocks/CU.
__global__ __launch_bounds__(256, 2) void so3_kernel(
    const float* __restrict__ x,
    const float* __restrict__ fw,
    const float* __restrict__ fb,
    float* __restrict__ out)
{
    __shared__ float tile[64][257];   // read bank (lane+k)%32: 2-way, free
    __shared__ float part[64][37];    // bank (5*lane+c)%32: 2-way, free

    const int t    = threadIdx.x;
    const int lane = t & 63;
    const int wv   = __builtin_amdgcn_readfirstlane(t >> 6);   // wave id 0..3

    const int r0 = blockIdx.x << 8;

    // stage permutation: thread t, instr i -> float4 idx  i*256 + (t&3)*64 + (t>>2)
    //   -> LDS row 4i+(t&3), col4 t>>2.  Write bank = (4i + (lane&31-perm))%32:
    //   exactly lane&31 -> conflict-free writes; global instr = 4x256B segments.
    const int srow4 = t & 3;
    const int scol4 = t >> 2;
    const float4* x4 = reinterpret_cast<const float4*>(x);
    const size_t bbase = (size_t)blockIdx.x * 16384;   // float4s per block

    // prologue: prefetch phase 0 (64 KB)
    float4 pre[16];
#pragma unroll
    for (int i = 0; i < 16; ++i)
        pre[i] = x4[bbase + (size_t)i * 256 + srow4 * 64 + scol4];

    float y[9];
#pragma unroll
    for (int j = 0; j < 9; ++j) y[j] = 0.f;

    for (int p = 0; p < 4; ++p) {
        if (p) __syncthreads();          // tile & part safe to overwrite

        // stage prefetched 64 rows (conflict-free b32 writes)
#pragma unroll
        for (int i = 0; i < 16; ++i) {
            const int row = (i << 2) + srow4;
            const int c   = scol4 << 2;
            tile[row][c + 0] = pre[i].x;
            tile[row][c + 1] = pre[i].y;
            tile[row][c + 2] = pre[i].z;
            tile[row][c + 3] = pre[i].w;
        }

        // issue next phase's loads; they fly over this phase's compute
        if (p < 3) {
            const size_t nb = bbase + (size_t)(p + 1) * 4096;
#pragma unroll
            for (int i = 0; i < 16; ++i)
                pre[i] = x4[nb + (size_t)i * 256 + srow4 * 64 + scol4];
        }
        __syncthreads();                 // tile ready

        // wave wv: partial dot over its 64-column slice for point q=lane
        float acc[9];
#pragma unroll
        for (int j = 0; j < 9; ++j) acc[j] = 0.f;
        const int kbase = wv << 6;       // wave-uniform (SGPR)
#pragma unroll
        for (int kk = 0; kk < 64; ++kk) {
            const int k = kbase + kk;
            const float xv = tile[lane][k];      // 2-way broadcast-free
#pragma unroll
            for (int j = 0; j < 9; ++j)
                acc[j] = fmaf(xv, fw[j * WIDTH + k], acc[j]);   // W: s_loads
        }
#pragma unroll
        for (int j = 0; j < 9; ++j) part[lane][wv * 9 + j] = acc[j];
        __syncthreads();                 // partials ready

        if (wv == p) {                   // wave p owns this phase's 64 points
#pragma unroll
            for (int j = 0; j < 9; ++j)
                y[j] = part[lane][j] + part[lane][9 + j]
                     + part[lane][18 + j] + part[lane][27 + j] + fb[j];
        }
    }

    // ---- fp32 3x3 special Procrustes:  R = U diag(1,1,det) V^T ----
    const float m00 = y[0], m01 = y[1], m02 = y[2];
    const float m10 = y[3], m11 = y[4], m12 = y[5];
    const float m20 = y[6], m21 = y[7], m22 = y[8];

    float a00 = m00*m00 + m10*m10 + m20*m20;
    float a01 = m00*m01 + m10*m11 + m20*m21;
    float a02 = m00*m02 + m10*m12 + m20*m22;
    float a11 = m01*m01 + m11*m11 + m21*m21;
    float a12 = m01*m02 + m11*m12 + m21*m22;
    float a22 = m02*m02 + m12*m12 + m22*m22;

    float v[3][3] = { {1,0,0}, {0,1,0}, {0,0,1} };

#pragma unroll
    for (int sw = 0; sw < 5; ++sw) {
        jrot(a00, a11, a01, a02, a12,
             v[0][0], v[0][1], v[1][0], v[1][1], v[2][0], v[2][1]);
        jrot(a00, a22, a02, a01, a12,
             v[0][0], v[0][2], v[1][0], v[1][2], v[2][0], v[2][2]);
        jrot(a11, a22, a12, a01, a02,
             v[0][1], v[0][2], v[1][1], v[1][2], v[2][1], v[2][2]);
    }

    float d0 = a00, d1 = a11, d2 = a22, tmp;
    if (d0 < d1) { tmp=d0; d0=d1; d1=tmp;
        tmp=v[0][0]; v[0][0]=v[0][1]; v[0][1]=tmp;
        tmp=v[1][0]; v[1][0]=v[1][1]; v[1][1]=tmp;
        tmp=v[2][0]; v[2][0]=v[2][1]; v[2][1]=tmp; }
    if (d0 < d2) { tmp=d0; d0=d2; d2=tmp;
        tmp=v[0][0]; v[0][0]=v[0][2]; v[0][2]=tmp;
        tmp=v[1][0]; v[1][0]=v[1][2]; v[1][2]=tmp;
        tmp=v[2][0]; v[2][0]=v[2][2]; v[2][2]=tmp; }
    if (d1 < d2) { tmp=d1; d1=d2; d2=tmp;
        tmp=v[0][1]; v[0][1]=v[0][2]; v[0][2]=tmp;
        tmp=v[1][1]; v[1][1]=v[1][2]; v[1][2]=tmp;
        tmp=v[2][1]; v[2][1]=v[2][2]; v[2][2]=tmp; }

    const float v1x = v[0][0], v1y = v[1][0], v1z = v[2][0];
    const float v2x = v[0][1], v2y = v[1][1], v2z = v[2][1];

    // u1 = normalize(M v1)
    float u1x = m00*v1x + m01*v1y + m02*v1z;
    float u1y = m10*v1x + m11*v1y + m12*v1z;
    float u1z = m20*v1x + m21*v1y + m22*v1z;
    float inv1 = 1.0f / (sqrtf(u1x*u1x + u1y*u1y + u1z*u1z) + 1e-30f);
    u1x *= inv1; u1y *= inv1; u1z *= inv1;

    // u2 = normalize(M v2 - (u1 . M v2) u1)
    float u2x = m00*v2x + m01*v2y + m02*v2z;
    float u2y = m10*v2x + m11*v2y + m12*v2z;
    float u2z = m20*v2x + m21*v2y + m22*v2z;
    const float d12 = u1x*u2x + u1y*u2y + u1z*u2z;
    u2x -= d12*u1x; u2y -= d12*u1y; u2z -= d12*u1z;
    float inv2 = 1.0f / (sqrtf(u2x*u2x + u2y*u2y + u2z*u2z) + 1e-30f);
    u2x *= inv2; u2y *= inv2; u2z *= inv2;

    // u3 = u1 x u2 ; v3 = v1 x v2
    const float u3x = u1y*u2z - u1z*u2y;
    const float u3y = u1z*u2x - u1x*u2z;
    const float u3z = u1x*u2y - u1y*u2x;
    const float v3x = v1y*v2z - v1z*v2y;
    const float v3y = v1z*v2x - v1x*v2z;
    const float v3z = v1x*v2y - v1y*v2x;

    float r[9];
    r[0] = u1x*v1x + u2x*v2x + u3x*v3x;
    r[1] = u1x*v1y + u2x*v2y + u3x*v3y;
    r[2] = u1x*v1z + u2x*v2z + u3x*v3z;
    r[3] = u1y*v1x + u2y*v2x + u3y*v3x;
    r[4] = u1y*v1y + u2y*v2y + u3y*v3y;
    r[5] = u1y*v1z + u2y*v2z + u3y*v3z;
    r[6] = u1z*v1x + u2z*v2x + u3z*v3x;
    r[7] = u1z*v1y + u2z*v2y + u3z*v3y;
    r[8] = u1z*v1z + u2z*v2z + u3z*v3z;

    float* o = out + (size_t)(r0 + t) * 9;
#pragma unroll
    for (int j = 0; j < 9; ++j) o[j] = r[j];
}

extern "C" void kernel_launch(void* const* d_in, const int* in_sizes, int n_in,
                              void* d_out, int out_size, void* d_ws, size_t ws_size,
                              hipStream_t stream) {
    const float* x  = (const float*)d_in[0];
    const float* fw = (const float*)d_in[1];
    const float* fb = (const float*)d_in[2];
    float* out = (float*)d_out;
    dim3 grid(N_PTS / 256), block(256);
    hipLaunchKernelGGL(so3_kernel, grid, block, 0, stream, x, fw, fb, out);
}